// Round 1
// baseline (163.587 us; speedup 1.0000x reference)
//
#include <hip/hip_runtime.h>

// Problem constants (from reference): E=4 edge types, B=262144 tokens, C=128 dim
#define N_E 4
#define N_B 262144
#define N_C 128

typedef __attribute__((ext_vector_type(8))) short bf16x8;   // 8 bf16 = 4 VGPRs (MFMA A/B frag)
typedef __attribute__((ext_vector_type(4))) float f32x4;    // MFMA C/D frag
typedef __attribute__((ext_vector_type(4))) unsigned int u32x4;

// fp32 -> bf16 round-to-nearest-even (bit trick; inputs are finite randoms)
__device__ __forceinline__ unsigned short f2bf(float f) {
  unsigned u = __float_as_uint(f);
  return (unsigned short)((u + 0x7FFFu + ((u >> 16) & 1u)) >> 16);
}

// out[b][d] = sum_e sum_c xs[e][b][c] * Ws[e][c][d]  + sum_e bs[e][d]
// GEMM: M=262144 (b), N=128 (d), K=512 (e,c). Memory-bound: stream xs once.
//
// Block: 512 threads = 8 waves. Wave w computes rows [blk*128 + w*16, +16) x all 128 cols.
// W staged per-e into LDS as bf16 in fragment-ready layout:
//   entry (u, d) = 8 bf16 at k = u*8+j (u = (kt*4 + hi), hi = lane>>4), 16B per entry.
// A loaded per-wave straight from global (8 contiguous fp32 per lane per k-chunk).
__global__ void __launch_bounds__(512)
grouped_gemm(const float* __restrict__ xs, const float* __restrict__ Ws,
             const float* __restrict__ bs, float* __restrict__ out) {
  // 16 k-groups x 128 cols x 8 bf16 = 32 KiB
  __shared__ unsigned short lds_w[16 * 128 * 8];
  __shared__ float lds_bias[128];

  const int tid  = threadIdx.x;
  const int lane = tid & 63;
  const int wave = tid >> 6;       // 0..7
  const int l15  = lane & 15;      // row-within-tile (A) / col-within-frag (B)
  const int hi   = lane >> 4;      // 0..3: k-subgroup

  const int waveRow = blockIdx.x * 128 + wave * 16;

  // bias[d] = sum_e bs[e][d]  (done once, covered by the e=0 barrier)
  if (tid < 128) {
    lds_bias[tid] = bs[tid] + bs[128 + tid] + bs[256 + tid] + bs[384 + tid];
  }

  f32x4 acc[8];
#pragma unroll
  for (int n = 0; n < 8; ++n) {
    f32x4 z = {0.0f, 0.0f, 0.0f, 0.0f};
    acc[n] = z;
  }

  // lane's A row pointer (row = waveRow + l15), advanced per e
  const float* xrow_base = xs + (size_t)(waveRow + l15) * N_C;

  for (int e = 0; e < N_E; ++e) {
    __syncthreads();  // protect lds_w overwrite (and publish lds_bias at e==0)

    // ---- stage Ws[e] (128x128 fp32) -> LDS bf16, fragment layout ----
    // 2048 entries of 16B; 512 threads x 4 entries. Entry n: u=n>>7 (k-group), d=n&127.
    {
      const float* We = Ws + (size_t)e * N_C * N_C;
#pragma unroll
      for (int i = 0; i < 4; ++i) {
        int n = tid + i * 512;
        int u = n >> 7;
        int d = n & 127;
        const float* src = We + u * 8 * N_C + d;  // column d, rows u*8..u*8+7
        float v[8];
#pragma unroll
        for (int j = 0; j < 8; ++j) v[j] = src[j * N_C];  // coalesced across lanes (d consecutive)
        u32x4 pk;
#pragma unroll
        for (int j = 0; j < 4; ++j)
          pk[j] = (unsigned)f2bf(v[2 * j]) | ((unsigned)f2bf(v[2 * j + 1]) << 16);
        *reinterpret_cast<u32x4*>(&lds_w[n * 8]) = pk;  // contiguous 16B/lane: conflict-free
      }
    }
    __syncthreads();

    // ---- compute this e: K=128 in 4 chunks of 32 ----
    const float* xrow = xrow_base + (size_t)e * N_B * N_C;
#pragma unroll
    for (int kt = 0; kt < 4; ++kt) {
      // A frag: lane holds xs[e][waveRow+l15][kt*32 + hi*8 + 0..7] (32B contiguous)
      const float* ap = xrow + kt * 32 + hi * 8;
      f32x4 a0 = *reinterpret_cast<const f32x4*>(ap);
      f32x4 a1 = *reinterpret_cast<const f32x4*>(ap + 4);
      bf16x8 afrag;
#pragma unroll
      for (int j = 0; j < 4; ++j) {
        afrag[j]     = (short)f2bf(a0[j]);
        afrag[4 + j] = (short)f2bf(a1[j]);
      }
      // B frags: one ds_read_b128 each; entry (kt*4+hi, n*16+l15)
      const unsigned short* wbase = &lds_w[(size_t)((kt * 4 + hi) * 128 + l15) * 8];
#pragma unroll
      for (int n = 0; n < 8; ++n) {
        bf16x8 bfrag = *reinterpret_cast<const bf16x8*>(wbase + (size_t)n * 16 * 8);
        acc[n] = __builtin_amdgcn_mfma_f32_16x16x32_bf16(afrag, bfrag, acc[n], 0, 0, 0);
      }
    }
  }

  // ---- epilogue: + bias, store. C/D layout: col = lane&15, row = (lane>>4)*4 + reg ----
#pragma unroll
  for (int n = 0; n < 8; ++n) {
    int d = n * 16 + l15;
    float bias = lds_bias[d];
#pragma unroll
    for (int r = 0; r < 4; ++r) {
      int row = waveRow + hi * 4 + r;
      out[(size_t)row * N_C + d] = acc[n][r] + bias;
    }
  }
}

extern "C" void kernel_launch(void* const* d_in, const int* in_sizes, int n_in,
                              void* d_out, int out_size, void* d_ws, size_t ws_size,
                              hipStream_t stream) {
  const float* xs = (const float*)d_in[0];  // [4][262144][128] fp32
  const float* Ws = (const float*)d_in[1];  // [4][128][128] fp32
  const float* bs = (const float*)d_in[2];  // [4][128] fp32
  float* out = (float*)d_out;               // [262144][128] fp32

  dim3 grid(N_B / 128);   // 2048 blocks, no tail (262144 % 128 == 0)
  dim3 block(512);
  hipLaunchKernelGGL(grouped_gemm, grid, block, 0, stream, xs, Ws, bs, out);
}